// Round 13
// baseline (169.281 us; speedup 1.0000x reference)
//
#include <hip/hip_runtime.h>
#include <hip/hip_bf16.h>

#define N_NODES 50000
#define N_EDGES 400000
#define IN_CH 1024
#define FEAT 128
#define HID 32
#define OUT_CH 3

#define GBM 64    // gemm row tile (782 blocks -> ~3 blocks/CU, balanced)
#define GBK 64    // gemm k tile

typedef short bf16x8 __attribute__((ext_vector_type(8)));
typedef float f32x4 __attribute__((ext_vector_type(4)));

static __device__ __forceinline__ unsigned short f2bf(float x) {
  unsigned int u = __float_as_uint(x);
  return (unsigned short)((u + 0x7FFFu + ((u >> 16) & 1u)) >> 16);  // RNE
}
static __device__ __forceinline__ float bflo(unsigned v) { return __uint_as_float(v << 16); }
static __device__ __forceinline__ float bfhi(unsigned v) { return __uint_as_float(v & 0xFFFF0000u); }

static __device__ __forceinline__ bf16x8 cvt8(const float4 a, const float4 b) {
  __hip_bfloat162 p0 = __float22bfloat162_rn({a.x, a.y});
  __hip_bfloat162 p1 = __float22bfloat162_rn({a.z, a.w});
  __hip_bfloat162 p2 = __float22bfloat162_rn({b.x, b.y});
  __hip_bfloat162 p3 = __float22bfloat162_rn({b.z, b.w});
  bf16x8 u;
  u[0] = *(short*)&p0.x; u[1] = *(short*)&p0.y;
  u[2] = *(short*)&p1.x; u[3] = *(short*)&p1.y;
  u[4] = *(short*)&p2.x; u[5] = *(short*)&p2.y;
  u[6] = *(short*)&p3.x; u[7] = *(short*)&p3.y;
  return u;
}

// async global->LDS, 16B/lane; LDS dest = wave-uniform base + lane*16
static __device__ __forceinline__ void gl16(const void* g, void* l) {
  __builtin_amdgcn_global_load_lds(
      (const __attribute__((address_space(1))) unsigned int*)g,
      (__attribute__((address_space(3))) unsigned int*)l, 16, 0, 0);
}

// ---- convert W_l,W_r into concat bf16 [256][1024]; also zeroes cnt
__global__ void convert_w(const float* __restrict__ Wl, const float* __restrict__ Wr,
                          unsigned short* __restrict__ wbf, int* __restrict__ cnt) {
  const int gtid = blockIdx.x * blockDim.x + threadIdx.x;
  const int stride = gridDim.x * blockDim.x;
  for (int i = gtid; i < 2 * FEAT * IN_CH; i += stride) {
    int row = i >> 10;
    float v = (row < FEAT) ? Wl[i] : Wr[i - FEAT * IN_CH];
    wbf[i] = f2bf(v);
  }
  for (int i = gtid; i < N_NODES; i += stride) cnt[i] = 0;
}

// ---- gemm: GBM=64, 48KB LDS -> 3 blocks/CU (3 waves/SIMD), 782 balanced blocks.
// Row-major linear LDS + XOR chunk swizzle on BOTH global source and ds_read.
//   A LDS: [64 rows][256B]   chunk(16B) at (r,c) holds logical chunk c^(r&15)
//   B LDS: [256 rows][128B]  chunk at (r,c) holds logical chunk c^(r&7)
__global__ __launch_bounds__(256, 3) void gemm_y(const float* __restrict__ feat,
                                                 const unsigned short* __restrict__ wbf,
                                                 unsigned short* __restrict__ Ybf,
                                                 unsigned short* __restrict__ Yrbf) {
  __shared__ __align__(16) char smem[49152];  // A: 16KB f32 | B: 32KB bf16
  char* aL = smem;
  char* bL = smem + 16384;
  const int t = threadIdx.x;
  const int lane = t & 63;
  const int w = t >> 6;              // 4 waves
  const int wm = w >> 1, wn = w & 1; // 2M x 2N; wave tile 32 x 128
  const int R0 = blockIdx.x * GBM;

  int goA[4], goB[8];
#pragma unroll
  for (int j = 0; j < 4; ++j) {
    int c16 = j * 256 + t;             // A chunk index [0,1024)
    int row = c16 >> 4, cpos = c16 & 15;
    int phys = cpos ^ (row & 15);
    int grow = R0 + row; grow = grow < N_NODES ? grow : N_NODES - 1;
    goA[j] = grow * (IN_CH * 4) + phys * 16;
  }
#pragma unroll
  for (int j = 0; j < 8; ++j) {
    int c16 = j * 256 + t;             // B chunk index [0,2048)
    int row = c16 >> 3, cpos = c16 & 7;
    int phys = cpos ^ (row & 7);
    goB[j] = row * (IN_CH * 2) + phys * 16;
  }
  const char* featB = (const char*)feat;
  const char* wbfB = (const char*)wbf;

  f32x4 acc[2][8];
#pragma unroll
  for (int m = 0; m < 2; ++m)
#pragma unroll
    for (int n = 0; n < 8; ++n) acc[m][n] = (f32x4){0.f, 0.f, 0.f, 0.f};

  const int r16 = lane & 15, kq = lane >> 4;

  for (int it = 0; it < IN_CH / GBK; ++it) {
    const int K0 = it * GBK;
#pragma unroll
    for (int j = 0; j < 4; ++j)
      gl16(featB + goA[j] + K0 * 4, aL + j * 4096 + w * 1024);
#pragma unroll
    for (int j = 0; j < 8; ++j)
      gl16(wbfB + goB[j] + K0 * 2, bL + j * 4096 + w * 1024);
    __syncthreads();
#pragma unroll
    for (int ks = 0; ks < 2; ++ks) {
      bf16x8 av[2], bv[8];
#pragma unroll
      for (int m = 0; m < 2; ++m) {
        const int row = wm * 32 + m * 16 + r16;
        const int l0 = ks * 8 + kq * 2;
        const int sw = row & 15;
        const float4 lo = *(const float4*)(aL + row * 256 + ((l0) ^ sw) * 16);
        const float4 hi = *(const float4*)(aL + row * 256 + ((l0 + 1) ^ sw) * 16);
        av[m] = cvt8(lo, hi);
      }
#pragma unroll
      for (int n = 0; n < 8; ++n) {
        const int row = wn * 128 + n * 16 + r16;
        const int l = ks * 4 + kq;
        bv[n] = *(const bf16x8*)(bL + row * 128 + ((l) ^ (row & 7)) * 16);
      }
#pragma unroll
      for (int m = 0; m < 2; ++m)
#pragma unroll
        for (int n = 0; n < 8; ++n)
          acc[m][n] = __builtin_amdgcn_mfma_f32_16x16x32_bf16(av[m], bv[n], acc[m][n], 0, 0, 0);
    }
    __syncthreads();
  }

  const int kq4 = lane >> 4;
  unsigned short* dst = (wn == 0) ? Ybf : Yrbf;
#pragma unroll
  for (int m = 0; m < 2; ++m) {
#pragma unroll
    for (int reg = 0; reg < 4; ++reg) {
      int row = R0 + wm * 32 + m * 16 + kq4 * 4 + reg;
      if (row < N_NODES) {
#pragma unroll
        for (int n = 0; n < 8; ++n)
          dst[(size_t)row * FEAT + n * 16 + r16] = f2bf(acc[m][n][reg]);
      }
    }
  }
}

// ---- CSR build (cnt pre-zeroed by convert_w)
__global__ __launch_bounds__(256) void deg_kernel(const int* __restrict__ e2,
                                                  int* __restrict__ cnt) {
  int e = blockIdx.x * 256 + threadIdx.x;
  if (e < N_EDGES) atomicAdd(&cnt[e2[N_EDGES + e]], 1);
}

// block-wide exclusive scan of one value per thread (256 threads, 4 waves)
static __device__ __forceinline__ int blockScanExcl(int v, int t, int* wsum) {
  int incl = v;
#pragma unroll
  for (int off = 1; off < 64; off <<= 1) {
    int u = __shfl_up(incl, off);
    if ((t & 63) >= off) incl += u;
  }
  const int wid = t >> 6;
  if ((t & 63) == 63) wsum[wid] = incl;
  __syncthreads();
  int base = 0;
#pragma unroll
  for (int k = 0; k < 4; ++k)
    if (k < wid) base += wsum[k];
  return base + incl - v;
}

#define SCAN_B ((N_NODES + 255) / 256)  // 196

__global__ __launch_bounds__(256) void scanA(const int* __restrict__ cnt,
                                             int* __restrict__ bsum) {
  __shared__ int lds[4];
  const int t = threadIdx.x;
  const int i = blockIdx.x * 256 + t;
  int v = (i < N_NODES) ? cnt[i] : 0;
  int s = v;
#pragma unroll
  for (int off = 32; off > 0; off >>= 1) s += __shfl_down(s, off);
  if ((t & 63) == 0) lds[t >> 6] = s;
  __syncthreads();
  if (t == 0) bsum[blockIdx.x] = lds[0] + lds[1] + lds[2] + lds[3];
}

__global__ __launch_bounds__(256) void scanB(const int* __restrict__ bsum,
                                             int* __restrict__ boff) {
  __shared__ int wsum[4];
  const int t = threadIdx.x;
  int v = (t < SCAN_B) ? bsum[t] : 0;
  int e = blockScanExcl(v, t, wsum);
  if (t < SCAN_B) boff[t] = e;
}

__global__ __launch_bounds__(256) void scanC(const int* __restrict__ cnt,
                                             const int* __restrict__ boff,
                                             int* __restrict__ rowptr) {
  __shared__ int wsum[4];
  const int t = threadIdx.x;
  const int i = blockIdx.x * 256 + t;
  int v = (i < N_NODES) ? cnt[i] : 0;
  int e = blockScanExcl(v, t, wsum);
  if (i < N_NODES) rowptr[i] = boff[blockIdx.x] + e;
  if (i == 0) rowptr[N_NODES] = N_EDGES;
}

// cursor counts DOWN from degree -> no re-zero needed
__global__ __launch_bounds__(256) void fill_kernel(const int* __restrict__ e2,
                                                   const int* __restrict__ rowptr,
                                                   int* __restrict__ cur,
                                                   int* __restrict__ csr_src) {
  int e = blockIdx.x * 256 + threadIdx.x;
  if (e < N_EDGES) {
    int src = e2[e];
    int dst = e2[N_EDGES + e];
    int pos = atomicAdd(&cur[dst], -1) - 1;
    csr_src[rowptr[dst] + pos] = src;
  }
}

// ---- fused gather-mean + SAGE combine + MLP tail. One wave per node, 8 nodes/wave.
#define NPB 32
__global__ __launch_bounds__(256) void gather_mlp(
    const int* __restrict__ rowptr, const int* __restrict__ csr_src,
    const unsigned short* __restrict__ Ybf, const unsigned short* __restrict__ Yrbf,
    const float* __restrict__ b_l,
    const float* __restrict__ fc1_w, const float* __restrict__ fc1_b,
    const float* __restrict__ fc2_w, const float* __restrict__ fc2_b,
    const float* __restrict__ gamma, const float* __restrict__ beta,
    const float* __restrict__ mean, const float* __restrict__ var,
    float* __restrict__ out) {
  __shared__ float wT[FEAT * 33];
  __shared__ float xs[4][FEAT];
  __shared__ float hsb[4][HID];
  __shared__ float w2s[OUT_CH * HID];
  const int t = threadIdx.x;
  const int wid = t >> 6, lane = t & 63;

  for (int idx = t; idx < HID * FEAT; idx += 256) {
    int h = idx >> 7, k = idx & 127;
    wT[k * 33 + h] = fc1_w[idx];
  }
  if (t < OUT_CH * HID) w2s[t] = fc2_w[t];
  const int h = lane & 31, half = lane >> 5;
  float bns, bnb, f1bh;
  {
    float g = gamma[h], mu = mean[h], v = var[h], b = beta[h];
    bns = g * rsqrtf(v + 1e-5f);
    bnb = b - mu * bns;
    f1bh = fc1_b[h];
  }
  const float2 bl2 = *(const float2*)(b_l + 2 * lane);
  __syncthreads();

  for (int i = 0; i < 8; ++i) {
    const int n = blockIdx.x * NPB + wid * 8 + i;
    if (n >= N_NODES) break;
    const int start = rowptr[n], end = rowptr[n + 1];
    float a0 = 0.f, a1 = 0.f;
    int j = start;
    for (; j + 3 < end; j += 4) {
      int s0 = csr_src[j], s1 = csr_src[j + 1], s2 = csr_src[j + 2], s3 = csr_src[j + 3];
      unsigned v0 = *(const unsigned*)(Ybf + (size_t)s0 * FEAT + 2 * lane);
      unsigned v1 = *(const unsigned*)(Ybf + (size_t)s1 * FEAT + 2 * lane);
      unsigned v2 = *(const unsigned*)(Ybf + (size_t)s2 * FEAT + 2 * lane);
      unsigned v3 = *(const unsigned*)(Ybf + (size_t)s3 * FEAT + 2 * lane);
      a0 += bflo(v0) + bflo(v1) + bflo(v2) + bflo(v3);
      a1 += bfhi(v0) + bfhi(v1) + bfhi(v2) + bfhi(v3);
    }
    for (; j < end; ++j) {
      unsigned v = *(const unsigned*)(Ybf + (size_t)csr_src[j] * FEAT + 2 * lane);
      a0 += bflo(v);
      a1 += bfhi(v);
    }
    const float rdeg = 1.0f / fmaxf((float)(end - start), 1.0f);
    const unsigned vy = *(const unsigned*)(Yrbf + (size_t)n * FEAT + 2 * lane);
    float x0 = a0 * rdeg + bl2.x + bflo(vy);
    float x1 = a1 * rdeg + bl2.y + bfhi(vy);
    x0 = x0 > 0.f ? x0 : 0.01f * x0;
    x1 = x1 > 0.f ? x1 : 0.01f * x1;
    xs[wid][2 * lane] = x0;
    xs[wid][2 * lane + 1] = x1;
    float p = 0.f;
    const float* xv = xs[wid] + half * 64;
    const float* wv = wT + (half * 64) * 33 + h;
#pragma unroll 16
    for (int k = 0; k < 64; ++k) p += wv[k * 33] * xv[k];
    p += __shfl_xor(p, 32);
    if (half == 0) {
      float a = fmaxf(p + f1bh, 0.f);
      hsb[wid][h] = a * bns + bnb;
    }
    if (lane < OUT_CH) {
      float o = fc2_b[lane];
#pragma unroll
      for (int k2 = 0; k2 < HID; ++k2) o += hsb[wid][k2] * w2s[lane * HID + k2];
      out[n * 3 + lane] = o;
    }
  }
}

extern "C" void kernel_launch(void* const* d_in, const int* in_sizes, int n_in,
                              void* d_out, int out_size, void* d_ws, size_t ws_size,
                              hipStream_t stream) {
  const float* feat = (const float*)d_in[0];
  const int* e2 = (const int*)d_in[2];
  const float* Wl = (const float*)d_in[5];
  const float* bl = (const float*)d_in[6];
  const float* Wr = (const float*)d_in[7];
  const float* f1w = (const float*)d_in[8];
  const float* f1b = (const float*)d_in[9];
  const float* f2w = (const float*)d_in[10];
  const float* f2b = (const float*)d_in[11];
  const float* gma = (const float*)d_in[12];
  const float* bta = (const float*)d_in[13];
  const float* mu = (const float*)d_in[14];
  const float* var = (const float*)d_in[15];
  float* out = (float*)d_out;

  char* ws = (char*)d_ws;
  unsigned short* wbf = (unsigned short*)ws;                        // 512 KB
  unsigned short* Ybf = (unsigned short*)(ws + 524288);             // 12.8 MB
  unsigned short* Yrbf = (unsigned short*)(ws + 524288 + 12800000); // 12.8 MB
  size_t off = 524288 + 12800000 + 12800000;
  int* rowptr = (int*)(ws + off);
  off += 200016;
  int* cnt = (int*)(ws + off);
  off += 200000;
  int* csr_src = (int*)(ws + off);
  off += (size_t)N_EDGES * 4;
  int* bsum = (int*)(ws + off);
  off += SCAN_B * 4;
  int* boff = (int*)(ws + off);

  const int EB = (N_EDGES + 255) / 256;
  convert_w<<<256, 256, 0, stream>>>(Wl, Wr, wbf, cnt);
  deg_kernel<<<EB, 256, 0, stream>>>(e2, cnt);
  scanA<<<SCAN_B, 256, 0, stream>>>(cnt, bsum);
  scanB<<<1, 256, 0, stream>>>(bsum, boff);
  scanC<<<SCAN_B, 256, 0, stream>>>(cnt, boff, rowptr);
  fill_kernel<<<EB, 256, 0, stream>>>(e2, rowptr, cnt, csr_src);
  gemm_y<<<(N_NODES + GBM - 1) / GBM, 256, 0, stream>>>(feat, wbf, Ybf, Yrbf);
  gather_mlp<<<(N_NODES + NPB - 1) / NPB, 256, 0, stream>>>(
      rowptr, csr_src, Ybf, Yrbf, bl, f1w, f1b, f2w, f2b, gma, bta, mu, var, out);
}

// Round 14
// 168.141 us; speedup vs baseline: 1.0068x; 1.0068x over previous
//
#include <hip/hip_runtime.h>
#include <hip/hip_bf16.h>

#define N_NODES 50000
#define N_EDGES 400000
#define IN_CH 1024
#define FEAT 128
#define HID 32
#define OUT_CH 3

#define GBM 128   // gemm row tile
#define GBK 32    // gemm k tile (one MFMA k-fragment)

typedef short bf16x8 __attribute__((ext_vector_type(8)));
typedef float f32x4 __attribute__((ext_vector_type(4)));

static __device__ __forceinline__ unsigned short f2bf(float x) {
  unsigned int u = __float_as_uint(x);
  return (unsigned short)((u + 0x7FFFu + ((u >> 16) & 1u)) >> 16);  // RNE
}
static __device__ __forceinline__ float bflo(unsigned v) { return __uint_as_float(v << 16); }
static __device__ __forceinline__ float bfhi(unsigned v) { return __uint_as_float(v & 0xFFFF0000u); }

static __device__ __forceinline__ bf16x8 cvt8(const float4 a, const float4 b) {
  __hip_bfloat162 p0 = __float22bfloat162_rn({a.x, a.y});
  __hip_bfloat162 p1 = __float22bfloat162_rn({a.z, a.w});
  __hip_bfloat162 p2 = __float22bfloat162_rn({b.x, b.y});
  __hip_bfloat162 p3 = __float22bfloat162_rn({b.z, b.w});
  bf16x8 u;
  u[0] = *(short*)&p0.x; u[1] = *(short*)&p0.y;
  u[2] = *(short*)&p1.x; u[3] = *(short*)&p1.y;
  u[4] = *(short*)&p2.x; u[5] = *(short*)&p2.y;
  u[6] = *(short*)&p3.x; u[7] = *(short*)&p3.y;
  return u;
}

// async global->LDS, 16B/lane; LDS dest = wave-uniform base + lane*16
static __device__ __forceinline__ void gl16(const void* g, void* l) {
  __builtin_amdgcn_global_load_lds(
      (const __attribute__((address_space(1))) unsigned int*)g,
      (__attribute__((address_space(3))) unsigned int*)l, 16, 0, 0);
}

// counted vmcnt + barrier fused (no compiler-inserted drain between)
#define WAIT_BAR(N) asm volatile("s_waitcnt vmcnt(" #N ")\n\ts_barrier" ::: "memory")
#define BARRIER() asm volatile("s_barrier" ::: "memory")

// ---- convert W_l,W_r into concat bf16 [256][1024]; also zeroes cnt
__global__ void convert_w(const float* __restrict__ Wl, const float* __restrict__ Wr,
                          unsigned short* __restrict__ wbf, int* __restrict__ cnt) {
  const int gtid = blockIdx.x * blockDim.x + threadIdx.x;
  const int stride = gridDim.x * blockDim.x;
  for (int i = gtid; i < 2 * FEAT * IN_CH; i += stride) {
    int row = i >> 10;
    float v = (row < FEAT) ? Wl[i] : Wr[i - FEAT * IN_CH];
    wbf[i] = f2bf(v);
  }
  for (int i = gtid; i < N_NODES; i += stride) cnt[i] = 0;
}

// ---- gemm: double-buffered (2x32KB), counted vmcnt(8), 2 blocks/CU resident.
//   A LDS: [128 rows][128B] f32; slot (r,c) holds logical chunk c^(r&7)   (8 slots)
//   B LDS: [256 rows][64B] bf16; slot (r,c) holds logical chunk c^(r&3)   (4 slots)
// Stage = 4 A + 4 B gl16 per thread per tile; source pre-swizzled (rule #21).
__global__ __launch_bounds__(256, 2) void gemm_y(const float* __restrict__ feat,
                                                 const unsigned short* __restrict__ wbf,
                                                 unsigned short* __restrict__ Ybf,
                                                 unsigned short* __restrict__ Yrbf) {
  __shared__ __align__(16) char smem[65536];  // 2 bufs x (A 16KB | B 16KB)
  const int t = threadIdx.x;
  const int lane = t & 63;
  const int w = t >> 6;              // 4 waves
  const int wm = w >> 1, wn = w & 1; // 2M x 2N; wave tile 64 x 128
  const int R0 = blockIdx.x * GBM;

  int goA[4], goB[4];
#pragma unroll
  for (int j = 0; j < 4; ++j) {
    {
      int c16 = j * 256 + t;             // A chunk [0,1024): row*8+slot
      int row = c16 >> 3, cpos = c16 & 7;
      int phys = cpos ^ (row & 7);
      int grow = R0 + row; grow = grow < N_NODES ? grow : N_NODES - 1;
      goA[j] = grow * (IN_CH * 4) + phys * 16;
    }
    {
      int c16 = j * 256 + t;             // B chunk [0,1024): row*4+slot
      int row = c16 >> 2, cpos = c16 & 3;
      int phys = cpos ^ (row & 3);
      goB[j] = row * (IN_CH * 2) + phys * 16;
    }
  }
  const char* featB = (const char*)feat;
  const char* wbfB = (const char*)wbf;

#define STAGE(K0, buf)                                                     \
  {                                                                        \
    char* aD = smem + (buf) * 32768;                                       \
    char* bD = aD + 16384;                                                 \
    _Pragma("unroll") for (int j = 0; j < 4; ++j)                          \
      gl16(featB + goA[j] + (K0) * 4, aD + j * 4096 + w * 1024);           \
    _Pragma("unroll") for (int j = 0; j < 4; ++j)                          \
      gl16(wbfB + goB[j] + (K0) * 2, bD + j * 4096 + w * 1024);            \
  }

  f32x4 acc[4][8];
#pragma unroll
  for (int m = 0; m < 4; ++m)
#pragma unroll
    for (int n = 0; n < 8; ++n) acc[m][n] = (f32x4){0.f, 0.f, 0.f, 0.f};

  const int r16 = lane & 15, kq = lane >> 4;
  const int NIT = IN_CH / GBK;  // 32

  STAGE(0, 0);

  for (int it = 0; it < NIT; ++it) {
    const int cur = it & 1;
    char* aC = smem + cur * 32768;
    char* bC = aC + 16384;
    if (it + 1 < NIT) {
      STAGE((it + 1) * GBK, cur ^ 1);  // 8 more in flight
      WAIT_BAR(8);                     // current tile done; next stays in flight
    } else {
      WAIT_BAR(0);
    }
    bf16x8 av[4], bv[8];
#pragma unroll
    for (int m = 0; m < 4; ++m) {
      const int row = wm * 64 + m * 16 + r16;
      const int sw = row & 7;
      const float4 lo = *(const float4*)(aC + row * 128 + ((kq * 2) ^ sw) * 16);
      const float4 hi = *(const float4*)(aC + row * 128 + ((kq * 2 + 1) ^ sw) * 16);
      av[m] = cvt8(lo, hi);
    }
#pragma unroll
    for (int n = 0; n < 8; ++n) {
      const int row = wn * 128 + n * 16 + r16;
      bv[n] = *(const bf16x8*)(bC + row * 64 + (kq ^ (row & 3)) * 16);
    }
#pragma unroll
    for (int m = 0; m < 4; ++m)
#pragma unroll
      for (int n = 0; n < 8; ++n)
        acc[m][n] = __builtin_amdgcn_mfma_f32_16x16x32_bf16(av[m], bv[n], acc[m][n], 0, 0, 0);
    BARRIER();  // all waves done with buf[cur] before it+1 stages into it
  }
#undef STAGE

  const int kq4 = lane >> 4;
  unsigned short* dst = (wn == 0) ? Ybf : Yrbf;
#pragma unroll
  for (int m = 0; m < 4; ++m) {
#pragma unroll
    for (int reg = 0; reg < 4; ++reg) {
      int row = R0 + wm * 64 + m * 16 + kq4 * 4 + reg;
      if (row < N_NODES) {
#pragma unroll
        for (int n = 0; n < 8; ++n)
          dst[(size_t)row * FEAT + n * 16 + r16] = f2bf(acc[m][n][reg]);
      }
    }
  }
}

// ---- CSR build (cnt pre-zeroed by convert_w)
__global__ __launch_bounds__(256) void deg_kernel(const int* __restrict__ e2,
                                                  int* __restrict__ cnt) {
  int e = blockIdx.x * 256 + threadIdx.x;
  if (e < N_EDGES) atomicAdd(&cnt[e2[N_EDGES + e]], 1);
}

// block-wide exclusive scan of one value per thread (256 threads, 4 waves)
static __device__ __forceinline__ int blockScanExcl(int v, int t, int* wsum) {
  int incl = v;
#pragma unroll
  for (int off = 1; off < 64; off <<= 1) {
    int u = __shfl_up(incl, off);
    if ((t & 63) >= off) incl += u;
  }
  const int wid = t >> 6;
  if ((t & 63) == 63) wsum[wid] = incl;
  __syncthreads();
  int base = 0;
#pragma unroll
  for (int k = 0; k < 4; ++k)
    if (k < wid) base += wsum[k];
  return base + incl - v;
}

#define SCAN_B ((N_NODES + 255) / 256)  // 196

__global__ __launch_bounds__(256) void scanA(const int* __restrict__ cnt,
                                             int* __restrict__ bsum) {
  __shared__ int lds[4];
  const int t = threadIdx.x;
  const int i = blockIdx.x * 256 + t;
  int v = (i < N_NODES) ? cnt[i] : 0;
  int s = v;
#pragma unroll
  for (int off = 32; off > 0; off >>= 1) s += __shfl_down(s, off);
  if ((t & 63) == 0) lds[t >> 6] = s;
  __syncthreads();
  if (t == 0) bsum[blockIdx.x] = lds[0] + lds[1] + lds[2] + lds[3];
}

__global__ __launch_bounds__(256) void scanB(const int* __restrict__ bsum,
                                             int* __restrict__ boff) {
  __shared__ int wsum[4];
  const int t = threadIdx.x;
  int v = (t < SCAN_B) ? bsum[t] : 0;
  int e = blockScanExcl(v, t, wsum);
  if (t < SCAN_B) boff[t] = e;
}

__global__ __launch_bounds__(256) void scanC(const int* __restrict__ cnt,
                                             const int* __restrict__ boff,
                                             int* __restrict__ rowptr) {
  __shared__ int wsum[4];
  const int t = threadIdx.x;
  const int i = blockIdx.x * 256 + t;
  int v = (i < N_NODES) ? cnt[i] : 0;
  int e = blockScanExcl(v, t, wsum);
  if (i < N_NODES) rowptr[i] = boff[blockIdx.x] + e;
  if (i == 0) rowptr[N_NODES] = N_EDGES;
}

// cursor counts DOWN from degree -> no re-zero needed
__global__ __launch_bounds__(256) void fill_kernel(const int* __restrict__ e2,
                                                   const int* __restrict__ rowptr,
                                                   int* __restrict__ cur,
                                                   int* __restrict__ csr_src) {
  int e = blockIdx.x * 256 + threadIdx.x;
  if (e < N_EDGES) {
    int src = e2[e];
    int dst = e2[N_EDGES + e];
    int pos = atomicAdd(&cur[dst], -1) - 1;
    csr_src[rowptr[dst] + pos] = src;
  }
}

// ---- fused gather-mean + SAGE combine + MLP tail. One wave per node, 8 nodes/wave.
#define NPB 32
__global__ __launch_bounds__(256) void gather_mlp(
    const int* __restrict__ rowptr, const int* __restrict__ csr_src,
    const unsigned short* __restrict__ Ybf, const unsigned short* __restrict__ Yrbf,
    const float* __restrict__ b_l,
    const float* __restrict__ fc1_w, const float* __restrict__ fc1_b,
    const float* __restrict__ fc2_w, const float* __restrict__ fc2_b,
    const float* __restrict__ gamma, const float* __restrict__ beta,
    const float* __restrict__ mean, const float* __restrict__ var,
    float* __restrict__ out) {
  __shared__ float wT[FEAT * 33];
  __shared__ float xs[4][FEAT];
  __shared__ float hsb[4][HID];
  __shared__ float w2s[OUT_CH * HID];
  const int t = threadIdx.x;
  const int wid = t >> 6, lane = t & 63;

  for (int idx = t; idx < HID * FEAT; idx += 256) {
    int h = idx >> 7, k = idx & 127;
    wT[k * 33 + h] = fc1_w[idx];
  }
  if (t < OUT_CH * HID) w2s[t] = fc2_w[t];
  const int h = lane & 31, half = lane >> 5;
  float bns, bnb, f1bh;
  {
    float g = gamma[h], mu = mean[h], v = var[h], b = beta[h];
    bns = g * rsqrtf(v + 1e-5f);
    bnb = b - mu * bns;
    f1bh = fc1_b[h];
  }
  const float2 bl2 = *(const float2*)(b_l + 2 * lane);
  __syncthreads();

  for (int i = 0; i < 8; ++i) {
    const int n = blockIdx.x * NPB + wid * 8 + i;
    if (n >= N_NODES) break;
    const int start = rowptr[n], end = rowptr[n + 1];
    float a0 = 0.f, a1 = 0.f;
    int j = start;
    for (; j + 3 < end; j += 4) {
      int s0 = csr_src[j], s1 = csr_src[j + 1], s2 = csr_src[j + 2], s3 = csr_src[j + 3];
      unsigned v0 = *(const unsigned*)(Ybf + (size_t)s0 * FEAT + 2 * lane);
      unsigned v1 = *(const unsigned*)(Ybf + (size_t)s1 * FEAT + 2 * lane);
      unsigned v2 = *(const unsigned*)(Ybf + (size_t)s2 * FEAT + 2 * lane);
      unsigned v3 = *(const unsigned*)(Ybf + (size_t)s3 * FEAT + 2 * lane);
      a0 += bflo(v0) + bflo(v1) + bflo(v2) + bflo(v3);
      a1 += bfhi(v0) + bfhi(v1) + bfhi(v2) + bfhi(v3);
    }
    for (; j < end; ++j) {
      unsigned v = *(const unsigned*)(Ybf + (size_t)csr_src[j] * FEAT + 2 * lane);
      a0 += bflo(v);
      a1 += bfhi(v);
    }
    const float rdeg = 1.0f / fmaxf((float)(end - start), 1.0f);
    const unsigned vy = *(const unsigned*)(Yrbf + (size_t)n * FEAT + 2 * lane);
    float x0 = a0 * rdeg + bl2.x + bflo(vy);
    float x1 = a1 * rdeg + bl2.y + bfhi(vy);
    x0 = x0 > 0.f ? x0 : 0.01f * x0;
    x1 = x1 > 0.f ? x1 : 0.01f * x1;
    xs[wid][2 * lane] = x0;
    xs[wid][2 * lane + 1] = x1;
    float p = 0.f;
    const float* xv = xs[wid] + half * 64;
    const float* wv = wT + (half * 64) * 33 + h;
#pragma unroll 16
    for (int k = 0; k < 64; ++k) p += wv[k * 33] * xv[k];
    p += __shfl_xor(p, 32);
    if (half == 0) {
      float a = fmaxf(p + f1bh, 0.f);
      hsb[wid][h] = a * bns + bnb;
    }
    if (lane < OUT_CH) {
      float o = fc2_b[lane];
#pragma unroll
      for (int k2 = 0; k2 < HID; ++k2) o += hsb[wid][k2] * w2s[lane * HID + k2];
      out[n * 3 + lane] = o;
    }
  }
}

extern "C" void kernel_launch(void* const* d_in, const int* in_sizes, int n_in,
                              void* d_out, int out_size, void* d_ws, size_t ws_size,
                              hipStream_t stream) {
  const float* feat = (const float*)d_in[0];
  const int* e2 = (const int*)d_in[2];
  const float* Wl = (const float*)d_in[5];
  const float* bl = (const float*)d_in[6];
  const float* Wr = (const float*)d_in[7];
  const float* f1w = (const float*)d_in[8];
  const float* f1b = (const float*)d_in[9];
  const float* f2w = (const float*)d_in[10];
  const float* f2b = (const float*)d_in[11];
  const float* gma = (const float*)d_in[12];
  const float* bta = (const float*)d_in[13];
  const float* mu = (const float*)d_in[14];
  const float* var = (const float*)d_in[15];
  float* out = (float*)d_out;

  char* ws = (char*)d_ws;
  unsigned short* wbf = (unsigned short*)ws;                        // 512 KB
  unsigned short* Ybf = (unsigned short*)(ws + 524288);             // 12.8 MB
  unsigned short* Yrbf = (unsigned short*)(ws + 524288 + 12800000); // 12.8 MB
  size_t off = 524288 + 12800000 + 12800000;
  int* rowptr = (int*)(ws + off);
  off += 200016;
  int* cnt = (int*)(ws + off);
  off += 200000;
  int* csr_src = (int*)(ws + off);
  off += (size_t)N_EDGES * 4;
  int* bsum = (int*)(ws + off);
  off += SCAN_B * 4;
  int* boff = (int*)(ws + off);

  const int EB = (N_EDGES + 255) / 256;
  convert_w<<<256, 256, 0, stream>>>(Wl, Wr, wbf, cnt);
  deg_kernel<<<EB, 256, 0, stream>>>(e2, cnt);
  scanA<<<SCAN_B, 256, 0, stream>>>(cnt, bsum);
  scanB<<<1, 256, 0, stream>>>(bsum, boff);
  scanC<<<SCAN_B, 256, 0, stream>>>(cnt, boff, rowptr);
  fill_kernel<<<EB, 256, 0, stream>>>(e2, rowptr, cnt, csr_src);
  gemm_y<<<(N_NODES + GBM - 1) / GBM, 256, 0, stream>>>(feat, wbf, Ybf, Yrbf);
  gather_mlp<<<(N_NODES + NPB - 1) / NPB, 256, 0, stream>>>(
      rowptr, csr_src, Ybf, Yrbf, bl, f1w, f1b, f2w, f2b, gma, bta, mu, var, out);
}

// Round 15
// 159.465 us; speedup vs baseline: 1.0616x; 1.0544x over previous
//
#include <hip/hip_runtime.h>
#include <hip/hip_bf16.h>

#define N_NODES 50000
#define N_EDGES 400000
#define IN_CH 1024
#define FEAT 128
#define HID 32
#define OUT_CH 3

#define GBM 128   // gemm row tile
#define GBK 64    // gemm k tile

typedef short bf16x8 __attribute__((ext_vector_type(8)));
typedef float f32x4 __attribute__((ext_vector_type(4)));

static __device__ __forceinline__ unsigned short f2bf(float x) {
  unsigned int u = __float_as_uint(x);
  return (unsigned short)((u + 0x7FFFu + ((u >> 16) & 1u)) >> 16);  // RNE
}
static __device__ __forceinline__ float bflo(unsigned v) { return __uint_as_float(v << 16); }
static __device__ __forceinline__ float bfhi(unsigned v) { return __uint_as_float(v & 0xFFFF0000u); }

static __device__ __forceinline__ bf16x8 cvt8(const float4 a, const float4 b) {
  __hip_bfloat162 p0 = __float22bfloat162_rn({a.x, a.y});
  __hip_bfloat162 p1 = __float22bfloat162_rn({a.z, a.w});
  __hip_bfloat162 p2 = __float22bfloat162_rn({b.x, b.y});
  __hip_bfloat162 p3 = __float22bfloat162_rn({b.z, b.w});
  bf16x8 u;
  u[0] = *(short*)&p0.x; u[1] = *(short*)&p0.y;
  u[2] = *(short*)&p1.x; u[3] = *(short*)&p1.y;
  u[4] = *(short*)&p2.x; u[5] = *(short*)&p2.y;
  u[6] = *(short*)&p3.x; u[7] = *(short*)&p3.y;
  return u;
}

// async global->LDS, 16B/lane; LDS dest = wave-uniform base + lane*16
static __device__ __forceinline__ void gl16(const void* g, void* l) {
  __builtin_amdgcn_global_load_lds(
      (const __attribute__((address_space(1))) unsigned int*)g,
      (__attribute__((address_space(3))) unsigned int*)l, 16, 0, 0);
}

// ---- convert W_l,W_r into concat bf16 [256][1024]; also zeroes cnt
__global__ void convert_w(const float* __restrict__ Wl, const float* __restrict__ Wr,
                          unsigned short* __restrict__ wbf, int* __restrict__ cnt) {
  const int gtid = blockIdx.x * blockDim.x + threadIdx.x;
  const int stride = gridDim.x * blockDim.x;
  for (int i = gtid; i < 2 * FEAT * IN_CH; i += stride) {
    int row = i >> 10;
    float v = (row < FEAT) ? Wl[i] : Wr[i - FEAT * IN_CH];
    wbf[i] = f2bf(v);
  }
  for (int i = gtid; i < N_NODES; i += stride) cnt[i] = 0;
}

// ---- gemm (R12 exact, best measured): single 64KB buffer, 256 thr, 2 blocks/CU.
// Row-major linear LDS + XOR chunk swizzle on BOTH global source and ds_read.
//   A LDS: [128 rows][256B]  chunk(16B) at (r,c) holds logical chunk c^(r&15)
//   B LDS: [256 rows][128B]  chunk at (r,c) holds logical chunk c^(r&7)
__global__ __launch_bounds__(256, 2) void gemm_y(const float* __restrict__ feat,
                                                 const unsigned short* __restrict__ wbf,
                                                 unsigned short* __restrict__ Ybf,
                                                 unsigned short* __restrict__ Yrbf) {
  __shared__ __align__(16) char smem[65536];  // A: 32KB f32 | B: 32KB bf16
  char* aL = smem;
  char* bL = smem + 32768;
  const int t = threadIdx.x;
  const int lane = t & 63;
  const int w = t >> 6;              // 4 waves
  const int wm = w >> 1, wn = w & 1; // 2M x 2N; wave tile 64 x 128
  const int R0 = blockIdx.x * GBM;

  int goA[8], goB[8];
#pragma unroll
  for (int j = 0; j < 8; ++j) {
    {
      int c16 = j * 256 + t;
      int row = c16 >> 4, cpos = c16 & 15;
      int phys = cpos ^ (row & 15);
      int grow = R0 + row; grow = grow < N_NODES ? grow : N_NODES - 1;
      goA[j] = grow * (IN_CH * 4) + phys * 16;
    }
    {
      int c16 = j * 256 + t;
      int row = c16 >> 3, cpos = c16 & 7;
      int phys = cpos ^ (row & 7);
      goB[j] = row * (IN_CH * 2) + phys * 16;
    }
  }
  const char* featB = (const char*)feat;
  const char* wbfB = (const char*)wbf;

  f32x4 acc[4][8];
#pragma unroll
  for (int m = 0; m < 4; ++m)
#pragma unroll
    for (int n = 0; n < 8; ++n) acc[m][n] = (f32x4){0.f, 0.f, 0.f, 0.f};

  const int r16 = lane & 15, kq = lane >> 4;

  for (int it = 0; it < IN_CH / GBK; ++it) {
    const int K0 = it * GBK;
#pragma unroll
    for (int j = 0; j < 8; ++j)
      gl16(featB + goA[j] + K0 * 4, aL + j * 4096 + w * 1024);
#pragma unroll
    for (int j = 0; j < 8; ++j)
      gl16(wbfB + goB[j] + K0 * 2, bL + j * 4096 + w * 1024);
    __syncthreads();
#pragma unroll
    for (int ks = 0; ks < 2; ++ks) {
      bf16x8 av[4], bv[8];
#pragma unroll
      for (int m = 0; m < 4; ++m) {
        const int row = wm * 64 + m * 16 + r16;
        const int l0 = ks * 8 + kq * 2;
        const int sw = row & 15;
        const float4 lo = *(const float4*)(aL + row * 256 + ((l0) ^ sw) * 16);
        const float4 hi = *(const float4*)(aL + row * 256 + ((l0 + 1) ^ sw) * 16);
        av[m] = cvt8(lo, hi);
      }
#pragma unroll
      for (int n = 0; n < 8; ++n) {
        const int row = wn * 128 + n * 16 + r16;
        const int l = ks * 4 + kq;
        bv[n] = *(const bf16x8*)(bL + row * 128 + ((l) ^ (row & 7)) * 16);
      }
#pragma unroll
      for (int m = 0; m < 4; ++m)
#pragma unroll
        for (int n = 0; n < 8; ++n)
          acc[m][n] = __builtin_amdgcn_mfma_f32_16x16x32_bf16(av[m], bv[n], acc[m][n], 0, 0, 0);
    }
    __syncthreads();
  }

  const int kq4 = lane >> 4;
  unsigned short* dst = (wn == 0) ? Ybf : Yrbf;
#pragma unroll
  for (int m = 0; m < 4; ++m) {
#pragma unroll
    for (int reg = 0; reg < 4; ++reg) {
      int row = R0 + wm * 64 + m * 16 + kq4 * 4 + reg;
      if (row < N_NODES) {
#pragma unroll
        for (int n = 0; n < 8; ++n)
          dst[(size_t)row * FEAT + n * 16 + r16] = f2bf(acc[m][n][reg]);
      }
    }
  }
}

// ---- CSR build (cnt pre-zeroed by convert_w)
__global__ __launch_bounds__(256) void deg_kernel(const int* __restrict__ e2,
                                                  int* __restrict__ cnt) {
  int e = blockIdx.x * 256 + threadIdx.x;
  if (e < N_EDGES) atomicAdd(&cnt[e2[N_EDGES + e]], 1);
}

// block-wide exclusive scan of one value per thread (256 threads, 4 waves)
static __device__ __forceinline__ int blockScanExcl(int v, int t, int* wsum) {
  int incl = v;
#pragma unroll
  for (int off = 1; off < 64; off <<= 1) {
    int u = __shfl_up(incl, off);
    if ((t & 63) >= off) incl += u;
  }
  const int wid = t >> 6;
  if ((t & 63) == 63) wsum[wid] = incl;
  __syncthreads();
  int base = 0;
#pragma unroll
  for (int k = 0; k < 4; ++k)
    if (k < wid) base += wsum[k];
  return base + incl - v;
}

#define SCAN_B ((N_NODES + 255) / 256)  // 196

__global__ __launch_bounds__(256) void scanA(const int* __restrict__ cnt,
                                             int* __restrict__ bsum) {
  __shared__ int lds[4];
  const int t = threadIdx.x;
  const int i = blockIdx.x * 256 + t;
  int v = (i < N_NODES) ? cnt[i] : 0;
  int s = v;
#pragma unroll
  for (int off = 32; off > 0; off >>= 1) s += __shfl_down(s, off);
  if ((t & 63) == 0) lds[t >> 6] = s;
  __syncthreads();
  if (t == 0) bsum[blockIdx.x] = lds[0] + lds[1] + lds[2] + lds[3];
}

// scanC: each block computes its own prefix over bsum (196 <= 256 threads),
// then rowptr = prefix + intra-block exclusive scan. (scanB eliminated.)
__global__ __launch_bounds__(256) void scanC(const int* __restrict__ cnt,
                                             const int* __restrict__ bsum,
                                             int* __restrict__ rowptr) {
  __shared__ int wsum[4];
  __shared__ int lds[4];
  __shared__ int pfx;
  const int t = threadIdx.x;
  const int bid = blockIdx.x;
  // prefix = sum of bsum[0..bid)
  int pv = (t < bid && t < SCAN_B) ? bsum[t] : 0;
  int s = pv;
#pragma unroll
  for (int off = 32; off > 0; off >>= 1) s += __shfl_down(s, off);
  if ((t & 63) == 0) lds[t >> 6] = s;
  __syncthreads();
  if (t == 0) pfx = lds[0] + lds[1] + lds[2] + lds[3];
  __syncthreads();
  const int i = bid * 256 + t;
  int v = (i < N_NODES) ? cnt[i] : 0;
  int e = blockScanExcl(v, t, wsum);
  if (i < N_NODES) rowptr[i] = pfx + e;
  if (i == 0) rowptr[N_NODES] = N_EDGES;
}

// cursor counts DOWN from degree -> no re-zero needed
__global__ __launch_bounds__(256) void fill_kernel(const int* __restrict__ e2,
                                                   const int* __restrict__ rowptr,
                                                   int* __restrict__ cur,
                                                   int* __restrict__ csr_src) {
  int e = blockIdx.x * 256 + threadIdx.x;
  if (e < N_EDGES) {
    int src = e2[e];
    int dst = e2[N_EDGES + e];
    int pos = atomicAdd(&cur[dst], -1) - 1;
    csr_src[rowptr[dst] + pos] = src;
  }
}

// ---- fused gather-mean + SAGE combine + MLP tail. One wave per node, 8 nodes/wave.
// Edge loop: branch-free predicated groups of 4 (no serial scalar tail).
#define NPB 32
__global__ __launch_bounds__(256) void gather_mlp(
    const int* __restrict__ rowptr, const int* __restrict__ csr_src,
    const unsigned short* __restrict__ Ybf, const unsigned short* __restrict__ Yrbf,
    const float* __restrict__ b_l,
    const float* __restrict__ fc1_w, const float* __restrict__ fc1_b,
    const float* __restrict__ fc2_w, const float* __restrict__ fc2_b,
    const float* __restrict__ gamma, const float* __restrict__ beta,
    const float* __restrict__ mean, const float* __restrict__ var,
    float* __restrict__ out) {
  __shared__ float wT[FEAT * 33];
  __shared__ float xs[4][FEAT];
  __shared__ float hsb[4][HID];
  __shared__ float w2s[OUT_CH * HID];
  const int t = threadIdx.x;
  const int wid = t >> 6, lane = t & 63;

  for (int idx = t; idx < HID * FEAT; idx += 256) {
    int h = idx >> 7, k = idx & 127;
    wT[k * 33 + h] = fc1_w[idx];
  }
  if (t < OUT_CH * HID) w2s[t] = fc2_w[t];
  const int h = lane & 31, half = lane >> 5;
  float bns, bnb, f1bh;
  {
    float g = gamma[h], mu = mean[h], v = var[h], b = beta[h];
    bns = g * rsqrtf(v + 1e-5f);
    bnb = b - mu * bns;
    f1bh = fc1_b[h];
  }
  const float2 bl2 = *(const float2*)(b_l + 2 * lane);
  __syncthreads();

  for (int i = 0; i < 8; ++i) {
    const int n = blockIdx.x * NPB + wid * 8 + i;
    if (n >= N_NODES) break;
    const int start = rowptr[n], end = rowptr[n + 1];
    float a0 = 0.f, a1 = 0.f;
    const int last = end - 1;
    for (int j = start; j < end; j += 4) {
      int j1 = j + 1 <= last ? j + 1 : last;
      int j2 = j + 2 <= last ? j + 2 : last;
      int j3 = j + 3 <= last ? j + 3 : last;
      int s0 = csr_src[j], s1 = csr_src[j1], s2 = csr_src[j2], s3 = csr_src[j3];
      float m1 = (j + 1 < end) ? 1.f : 0.f;
      float m2 = (j + 2 < end) ? 1.f : 0.f;
      float m3 = (j + 3 < end) ? 1.f : 0.f;
      unsigned v0 = *(const unsigned*)(Ybf + (size_t)s0 * FEAT + 2 * lane);
      unsigned v1 = *(const unsigned*)(Ybf + (size_t)s1 * FEAT + 2 * lane);
      unsigned v2 = *(const unsigned*)(Ybf + (size_t)s2 * FEAT + 2 * lane);
      unsigned v3 = *(const unsigned*)(Ybf + (size_t)s3 * FEAT + 2 * lane);
      a0 += bflo(v0) + m1 * bflo(v1) + m2 * bflo(v2) + m3 * bflo(v3);
      a1 += bfhi(v0) + m1 * bfhi(v1) + m2 * bfhi(v2) + m3 * bfhi(v3);
    }
    const float rdeg = 1.0f / fmaxf((float)(end - start), 1.0f);
    const unsigned vy = *(const unsigned*)(Yrbf + (size_t)n * FEAT + 2 * lane);
    float x0 = a0 * rdeg + bl2.x + bflo(vy);
    float x1 = a1 * rdeg + bl2.y + bfhi(vy);
    x0 = x0 > 0.f ? x0 : 0.01f * x0;
    x1 = x1 > 0.f ? x1 : 0.01f * x1;
    xs[wid][2 * lane] = x0;
    xs[wid][2 * lane + 1] = x1;
    float p = 0.f;
    const float* xv = xs[wid] + half * 64;
    const float* wv = wT + (half * 64) * 33 + h;
#pragma unroll 16
    for (int k = 0; k < 64; ++k) p += wv[k * 33] * xv[k];
    p += __shfl_xor(p, 32);
    if (half == 0) {
      float a = fmaxf(p + f1bh, 0.f);
      hsb[wid][h] = a * bns + bnb;
    }
    if (lane < OUT_CH) {
      float o = fc2_b[lane];
#pragma unroll
      for (int k2 = 0; k2 < HID; ++k2) o += hsb[wid][k2] * w2s[lane * HID + k2];
      out[n * 3 + lane] = o;
    }
  }
}

extern "C" void kernel_launch(void* const* d_in, const int* in_sizes, int n_in,
                              void* d_out, int out_size, void* d_ws, size_t ws_size,
                              hipStream_t stream) {
  const float* feat = (const float*)d_in[0];
  const int* e2 = (const int*)d_in[2];
  const float* Wl = (const float*)d_in[5];
  const float* bl = (const float*)d_in[6];
  const float* Wr = (const float*)d_in[7];
  const float* f1w = (const float*)d_in[8];
  const float* f1b = (const float*)d_in[9];
  const float* f2w = (const float*)d_in[10];
  const float* f2b = (const float*)d_in[11];
  const float* gma = (const float*)d_in[12];
  const float* bta = (const float*)d_in[13];
  const float* mu = (const float*)d_in[14];
  const float* var = (const float*)d_in[15];
  float* out = (float*)d_out;

  char* ws = (char*)d_ws;
  unsigned short* wbf = (unsigned short*)ws;                        // 512 KB
  unsigned short* Ybf = (unsigned short*)(ws + 524288);             // 12.8 MB
  unsigned short* Yrbf = (unsigned short*)(ws + 524288 + 12800000); // 12.8 MB
  size_t off = 524288 + 12800000 + 12800000;
  int* rowptr = (int*)(ws + off);
  off += 200016;
  int* cnt = (int*)(ws + off);
  off += 200000;
  int* csr_src = (int*)(ws + off);
  off += (size_t)N_EDGES * 4;
  int* bsum = (int*)(ws + off);

  const int EB = (N_EDGES + 255) / 256;
  convert_w<<<256, 256, 0, stream>>>(Wl, Wr, wbf, cnt);
  deg_kernel<<<EB, 256, 0, stream>>>(e2, cnt);
  scanA<<<SCAN_B, 256, 0, stream>>>(cnt, bsum);
  scanC<<<SCAN_B, 256, 0, stream>>>(cnt, bsum, rowptr);
  fill_kernel<<<EB, 256, 0, stream>>>(e2, rowptr, cnt, csr_src);
  gemm_y<<<(N_NODES + GBM - 1) / GBM, 256, 0, stream>>>(feat, wbf, Ybf, Yrbf);
  gather_mlp<<<(N_NODES + NPB - 1) / NPB, 256, 0, stream>>>(
      rowptr, csr_src, Ybf, Yrbf, bl, f1w, f1b, f2w, f2b, gma, bta, mu, var, out);
}